// Round 2
// baseline (515.215 us; speedup 1.0000x reference)
//
#include <hip/hip_runtime.h>

#define NRAYS 131072
#define NS 64      // coarse samples (z_vals per ray)
#define NI 128     // importance samples
#define NM 63      // bins (z_mid entries) == cdf length
#define NW 62      // interior weights used
#define NT 192     // merged samples per ray (NS + NI)

// One ray per wave64. cdf/z_mid/z_vals register-resident (one elem per lane).
// Merge is ANALYTIC: z_vals[L] is mapped through the forward CDF to u-space
// threshold U_L; its merge rank = #{j: u_j < U_L} computed in pure VALU
// (u is a linspace). Sample rank reuses the sampling binary search (lo) plus
// one gather of U_lo. Both sides decide each (L,j) pair by the SAME float
// comparison (u_j < U_L), so the 192 positions form an exact permutation.
__global__ __launch_bounds__(256) void importance_kernel(
    const float* __restrict__ rays_o,
    const float* __restrict__ rays_d,
    const float* __restrict__ z_vals,
    const float* __restrict__ weights,
    float* __restrict__ out_pts,    // [N, 192, 3]
    float* __restrict__ out_zall,   // [N, 192]
    float* __restrict__ out_zs)     // [N, 128]
{
    __shared__ __align__(16) float s_zall[4][NT];   // 3 KB/block

    const int wave = threadIdx.x >> 6;
    const int lane = threadIdx.x & 63;
    const int ray  = (blockIdx.x << 2) + wave;   // NRAYS % 4 == 0

    const float* zv_g = z_vals  + (size_t)ray * NS;
    const float* w_g  = weights + (size_t)ray * NS;

    // ---- inputs ----
    const float zvl = zv_g[lane];                      // z_vals[lane]
    const float wl  = (lane < NW) ? (w_g[lane + 1] + 1e-5f) : 0.0f;

    // o,d via wave-uniform scalar loads (s_load; no DS broadcast needed)
    const int sray = __builtin_amdgcn_readfirstlane(ray);
    const float o0 = rays_o[3 * sray + 0], o1 = rays_o[3 * sray + 1], o2 = rays_o[3 * sray + 2];
    const float d0 = rays_d[3 * sray + 0], d1 = rays_d[3 * sray + 1], d2 = rays_d[3 * sray + 2];

    // z_mid[lane] (valid lane<63)
    const float zm = 0.5f * (zvl + __shfl_down(zvl, 1, 64));

    // ---- inclusive scan of wl (Hillis-Steele over 64 lanes) ----
    float scan = wl;
    #pragma unroll
    for (int off = 1; off < 64; off <<= 1) {
        const float up = __shfl_up(scan, off, 64);
        if (lane >= off) scan += up;
    }
    const float total = __shfl(scan, NW - 1, 64);      // lane 61 = full sum
    const float sp  = __shfl_up(scan, 1, 64);
    const float cdf = (lane == 0) ? 0.0f : sp / total; // cdf[lane], lane<=62

    const float zm_m1  = __shfl_up(zm, 1, 64);         // zm[lane-1]
    const float cdf_m1 = __shfl_up(cdf, 1, 64);        // cdf[lane-1]

    // ---- U[lane]: u-space merge threshold for zv[lane] ----
    // U_L in [cdf[L-1], cdf[L]] enforced exactly (min/clamp) -> monotone.
    float U;
    {
        float rr = (zvl - zm_m1) / (zm - zm_m1);
        rr = fminf(fmaxf(rr, 0.0f), 1.0f);             // NaN/Inf -> clamped
        float dg = cdf - cdf_m1;
        if (dg < 1e-5f) dg = 1.0f;                     // same guard as sampler
        float uu = cdf_m1 + rr * dg;
        uu = fminf(uu, cdf);
        U = (lane == 0) ? 0.0f : ((lane == 63) ? 2.0f : uu);
    }

    // ---- zv merge rank: cnt = #{j in [0,128): u_j < U} (pure VALU) ----
    int cnt;
    if (lane == 0) cnt = 0;
    else if (lane == 63) cnt = 128;
    else {
        const int g = (int)(U * 127.0f);               // in [0,127]
        int c = g - 1;
        #pragma unroll
        for (int t = -1; t <= 1; ++t) {
            const int j = g + t;
            bool lt;
            if (j < 0) lt = true;
            else if (j > 127) lt = false;
            else lt = ((float)((double)j * (1.0 / 127.0)) < U);
            c += lt ? 1 : 0;
        }
        cnt = c;                                       // exact count
    }
    s_zall[wave][lane + cnt] = zvl;

    // ---- inverse-CDF sampling + sample merge rank ----
    // lane handles samples j = 2*lane, 2*lane+1 (so zs store is float2)
    float xs0, xs1;
    #pragma unroll
    for (int rep = 0; rep < 2; rep++) {
        const int j = (lane << 1) + rep;
        const float u = (float)((double)j * (1.0 / 127.0));
        // searchsorted(cdf, u, side='right') over cdf[0..62]; lo in [1,63]
        int lo = 0, hi = NM;
        #pragma unroll
        for (int it = 0; it < 6; it++) {
            const int mid = (lo + hi) >> 1;            // <= 62 while lo<hi
            const float v = __shfl(cdf, mid, 64);
            if (lo < hi) { if (v <= u) lo = mid + 1; else hi = mid; }
        }
        const int below = lo - 1;                      // >= 0 (cdf[0]=0<=u)
        const int above = (lo > NM - 1) ? (NM - 1) : lo;
        const float cb = __shfl(cdf, below, 64);
        const float ca = __shfl(cdf, above, 64);
        const float bb = __shfl(zm,  below, 64);
        const float ba = __shfl(zm,  above, 64);
        const float Ul = __shfl(U,   lo,    64);
        float denom = ca - cb;
        if (denom < 1e-5f) denom = 1.0f;
        const float t = (u - cb) / denom;
        const float x = bb + t * (ba - bb);
        // rank among z_vals: #{L: U_L <= u} == lo + (U_lo <= u)
        const int pos = j + lo + ((Ul <= u) ? 1 : 0);
        s_zall[wave][pos] = x;
        if (rep == 0) xs0 = x; else xs1 = x;
    }

    // Wave-local ordering: drain scatter ds_writes before re-reading.
    asm volatile("s_waitcnt lgkmcnt(0)" ::: "memory");

    // ---- outputs (all vectorized) ----
    const float* zallp = s_zall[wave];

    // pts: 576 floats/ray = 144 float4; lane i4 covers elems 4*i4..4*i4+3
    const size_t pts_base = (size_t)ray * (NT * 3);
    #pragma unroll
    for (int rep = 0; rep < 3; rep++) {
        const int i4 = lane + (rep << 6);
        if (i4 < 144) {
            const int q  = i4 / 3;
            const int m  = i4 - 3 * q;
            const int k0 = i4 + q;                     // = floor(4*i4/3)
            const float za = zallp[k0];
            const float zb = zallp[k0 + 1];            // k0+1 <= 191
            float4 v;
            #pragma unroll
            for (int t = 0; t < 4; t++) {
                const int mt = m + t;                  // 0..5
                const float z  = (mt >= 3) ? zb : za;
                const int  ds  = (mt >= 3) ? (mt - 3) : mt;   // (m+t)%3
                const float oo = (ds == 0) ? o0 : ((ds == 1) ? o1 : o2);
                const float dd = (ds == 0) ? d0 : ((ds == 1) ? d1 : d2);
                (&v.x)[t] = fmaf(dd, z, oo);
            }
            *reinterpret_cast<float4*>(out_pts + pts_base + ((size_t)i4 << 2)) = v;
        }
    }

    // zall: 192 floats = 48 float4 (ds_read_b128 + dwordx4 store)
    if (lane < 48) {
        const float4 v = *reinterpret_cast<const float4*>(&zallp[lane << 2]);
        *reinterpret_cast<float4*>(out_zall + (size_t)ray * NT + (lane << 2)) = v;
    }

    // zs: lane holds samples 2*lane, 2*lane+1 -> one float2 store
    {
        float2 zz; zz.x = xs0; zz.y = xs1;
        *reinterpret_cast<float2*>(out_zs + (size_t)ray * NI + (lane << 1)) = zz;
    }
}

extern "C" void kernel_launch(void* const* d_in, const int* in_sizes, int n_in,
                              void* d_out, int out_size, void* d_ws, size_t ws_size,
                              hipStream_t stream) {
    const float* rays_o  = (const float*)d_in[0];
    const float* rays_d  = (const float*)d_in[1];
    const float* z_vals  = (const float*)d_in[2];
    const float* weights = (const float*)d_in[3];

    float* out      = (float*)d_out;
    float* out_pts  = out;                                  // N*192*3
    float* out_zall = out + (size_t)NRAYS * NT * 3;         // N*192
    float* out_zs   = out_zall + (size_t)NRAYS * NT;        // N*128

    dim3 grid(NRAYS / 4), block(256);
    hipLaunchKernelGGL(importance_kernel, grid, block, 0, stream,
                       rays_o, rays_d, z_vals, weights,
                       out_pts, out_zall, out_zs);
}